// Round 1
// baseline (756.757 us; speedup 1.0000x reference)
//
#include <hip/hip_runtime.h>

typedef unsigned short u16;
typedef __attribute__((ext_vector_type(8))) short bfrag;   // 8 x bf16
typedef __attribute__((ext_vector_type(4))) float ffrag;   // 4 x f32

#define LN_EPS 1e-5f

__device__ __forceinline__ u16 f2bf(float f) {
    unsigned u = __builtin_bit_cast(unsigned, f);
    u += 0x7fffu + ((u >> 16) & 1u);   // RNE
    return (u16)(u >> 16);
}

// windowed token index -> image row index
__device__ __forceinline__ int win_to_img(int tok) {
    int win = tok >> 9, n = tok & 511;
    int wh = win >> 4, ww = (win >> 2) & 3, wd = win & 3;
    int ph = n >> 6, pw = (n >> 3) & 7, pd = n & 7;
    return ((wh * 8 + ph) * 32 + (ww * 8 + pw)) * 32 + (wd * 8 + pd);
}

// LayerNorm over C=512, one wave per token. windowed=1: read image order at
// gathered index, write windowed order. windowed=0: straight rows.
__global__ __launch_bounds__(256) void k_ln(const float* __restrict__ x,
                                            const float* __restrict__ w,
                                            const float* __restrict__ b,
                                            u16* __restrict__ out, int windowed) {
    int wave = threadIdx.x >> 6, lane = threadIdx.x & 63;
    int tok = blockIdx.x * 4 + wave;
    int src = windowed ? win_to_img(tok) : tok;
    const float* xr = x + (size_t)src * 512;
    float v[8];
#pragma unroll
    for (int i = 0; i < 2; i++) {
        float4 f = *(const float4*)(xr + i * 256 + lane * 4);
        v[i * 4 + 0] = f.x; v[i * 4 + 1] = f.y; v[i * 4 + 2] = f.z; v[i * 4 + 3] = f.w;
    }
    float s = 0.f;
#pragma unroll
    for (int i = 0; i < 8; i++) s += v[i];
#pragma unroll
    for (int m = 1; m < 64; m <<= 1) s += __shfl_xor(s, m);
    float mean = s * (1.0f / 512.0f);
    float vs = 0.f;
#pragma unroll
    for (int i = 0; i < 8; i++) { float d = v[i] - mean; vs += d * d; }
#pragma unroll
    for (int m = 1; m < 64; m <<= 1) vs += __shfl_xor(vs, m);
    float rstd = rsqrtf(vs * (1.0f / 512.0f) + LN_EPS);
    u16* orow = out + (size_t)tok * 512;
#pragma unroll
    for (int i = 0; i < 2; i++) {
        int c0 = i * 256 + lane * 4;
        ushort4 o;
        o.x = f2bf((v[i * 4 + 0] - mean) * rstd * w[c0 + 0] + b[c0 + 0]);
        o.y = f2bf((v[i * 4 + 1] - mean) * rstd * w[c0 + 1] + b[c0 + 1]);
        o.z = f2bf((v[i * 4 + 2] - mean) * rstd * w[c0 + 2] + b[c0 + 2]);
        o.w = f2bf((v[i * 4 + 3] - mean) * rstd * w[c0 + 3] + b[c0 + 3]);
        *(ushort4*)(orow + c0) = o;
    }
}

// in: f32 [K][Nn] row-major  ->  out: bf16 [Nn][K] (K contiguous)
__global__ __launch_bounds__(256) void k_transpose(const float* __restrict__ in,
                                                   u16* __restrict__ out, int K, int Nn) {
    int idx = blockIdx.x * 256 + threadIdx.x;
    if (idx >= K * Nn) return;
    int n = idx / K, k = idx - n * K;
    out[idx] = f2bf(in[(size_t)k * Nn + n]);
}

// q_ms f32 [8][512][64] -> bf16, pre-scaled by HD^-0.5 = 0.125
__global__ __launch_bounds__(256) void k_qconv(const float* __restrict__ q, u16* __restrict__ out) {
    int idx = blockIdx.x * 256 + threadIdx.x;
    out[idx] = f2bf(q[idx] * 0.125f);
}

// C = A[M,K](bf16, K-contig) @ Bt[N,K](bf16, K-contig)^T' + bias, epilogues:
// EPI 0: +bias -> bf16           (kv)
// EPI 1: +bias, scatter windowed->image, + resid(x) -> f32   (proj -> x1)
// EPI 2: +bias, exact GELU -> bf16                           (fc1 -> hid)
// EPI 3: +bias, + resid(x1) -> f32                           (fc2 -> out)
template <int EPI>
__global__ __launch_bounds__(256) void k_gemm(const u16* __restrict__ A,
                                              const u16* __restrict__ Bt,
                                              const float* __restrict__ bias,
                                              void* __restrict__ Cout, int K,
                                              const float* __restrict__ resid) {
    __shared__ u16 As[64][40];   // 80B row stride: 16B-aligned, 2-way bank alias (free)
    __shared__ u16 Bs[64][40];
    int wave = threadIdx.x >> 6, lane = threadIdx.x & 63;
    int bm = blockIdx.x, bn = blockIdx.y;
    int Nn = gridDim.y * 64;
    int ldrow = threadIdx.x >> 2;
    int ldk = (threadIdx.x & 3) * 8;
    const u16* Ag = A + (size_t)(bm * 64 + ldrow) * K + ldk;
    const u16* Bg = Bt + (size_t)(bn * 64 + ldrow) * K + ldk;
    ffrag acc[4] = {};
    int arow = (wave << 4) + (lane & 15);
    int koff = (lane >> 4) * 8;
    for (int k0 = 0; k0 < K; k0 += 32) {
        *(int4*)(&As[ldrow][ldk]) = *(const int4*)(Ag + k0);
        *(int4*)(&Bs[ldrow][ldk]) = *(const int4*)(Bg + k0);
        __syncthreads();
        bfrag a = *(const bfrag*)(&As[arow][koff]);
#pragma unroll
        for (int j = 0; j < 4; j++) {
            bfrag bb = *(const bfrag*)(&Bs[j * 16 + (lane & 15)][koff]);
            acc[j] = __builtin_amdgcn_mfma_f32_16x16x32_bf16(a, bb, acc[j], 0, 0, 0);
        }
        __syncthreads();
    }
    int row0 = bm * 64 + (wave << 4) + (lane >> 4) * 4;
    int colb = bn * 64 + (lane & 15);
#pragma unroll
    for (int j = 0; j < 4; j++) {
        int col = colb + j * 16;
        float bv = bias[col];
#pragma unroll
        for (int r = 0; r < 4; r++) {
            int row = row0 + r;
            float val = acc[j][r] + bv;
            if constexpr (EPI == 0) {
                ((u16*)Cout)[(size_t)row * Nn + col] = f2bf(val);
            } else if constexpr (EPI == 1) {
                int ri = win_to_img(row);
                size_t o = (size_t)ri * 512 + col;
                ((float*)Cout)[o] = val + resid[o];
            } else if constexpr (EPI == 2) {
                val = 0.5f * val * (1.0f + erff(val * 0.70710678118f));
                ((u16*)Cout)[(size_t)row * Nn + col] = f2bf(val);
            } else {
                size_t o = (size_t)row * 512 + col;
                ((float*)Cout)[o] = val + resid[o];
            }
        }
    }
}

// Flash attention: block = (q-chunk 64, head, window), 4 waves x 16 q-rows.
// qb: bf16 [8][512][64] (pre-scaled); kv: bf16 [32768][1024] (k | v per token);
// o: bf16 [32768][512] (windowed token order).
__global__ __launch_bounds__(256) void k_attn(const u16* __restrict__ qb,
                                              const u16* __restrict__ kv,
                                              u16* __restrict__ o) {
    __shared__ u16 Ks[64][72];    // [key][d]   144B stride: aligned, 2-way alias
    __shared__ u16 Vts[64][72];   // [d][key]
    __shared__ u16 Ps[64][72];    // [q][key]   wave-private row blocks
    int qc = blockIdx.x, hh = blockIdx.y, win = blockIdx.z;
    int wave = threadIdx.x >> 6, lane = threadIdx.x & 63;
    int t = threadIdx.x;
    const u16* qrow = qb + ((size_t)hh * 512 + qc * 64 + (wave << 4) + (lane & 15)) * 64 + (lane >> 4) * 8;
    bfrag aq0 = *(const bfrag*)(qrow);
    bfrag aq1 = *(const bfrag*)(qrow + 32);
    ffrag acc[4] = {};
    float m_run[4], l_run[4];
#pragma unroll
    for (int r = 0; r < 4; r++) { m_run[r] = -1e30f; l_run[r] = 0.0f; }
    const u16* kvw = kv + (size_t)win * 512 * 1024;
    int krow = t >> 2, kco = (t & 3) * 8;
    int vkt = t >> 2, vdb = (t & 3) * 16;
    int arow = (wave << 4) + (lane & 15);
    int koff = (lane >> 4) * 8;

    for (int kc = 0; kc < 8; kc++) {
        __syncthreads();   // prior iteration's K/V reads complete
        const u16* ksrc = kvw + (size_t)(kc * 64 + krow) * 1024 + hh * 64 + kco;
        *(int4*)(&Ks[krow][kco]) = *(const int4*)(ksrc);
        *(int4*)(&Ks[krow][kco + 32]) = *(const int4*)(ksrc + 32);
        const u16* vsrc = kvw + (size_t)(kc * 64 + vkt) * 1024 + 512 + hh * 64 + vdb;
        alignas(16) u16 tmp[16];
        *(int4*)(tmp) = *(const int4*)(vsrc);
        *(int4*)(tmp + 8) = *(const int4*)(vsrc + 8);
#pragma unroll
        for (int i = 0; i < 16; i++) Vts[vdb + i][vkt] = tmp[i];
        __syncthreads();

        ffrag s[4] = {};
#pragma unroll
        for (int j = 0; j < 4; j++) {
            bfrag b0 = *(const bfrag*)(&Ks[j * 16 + (lane & 15)][koff]);
            s[j] = __builtin_amdgcn_mfma_f32_16x16x32_bf16(aq0, b0, s[j], 0, 0, 0);
            bfrag b1 = *(const bfrag*)(&Ks[j * 16 + (lane & 15)][32 + koff]);
            s[j] = __builtin_amdgcn_mfma_f32_16x16x32_bf16(aq1, b1, s[j], 0, 0, 0);
        }
        // online softmax per q-row (row = (lane>>4)*4 + r; cols across 16 lanes x 4 frags)
#pragma unroll
        for (int r = 0; r < 4; r++) {
            float mx = fmaxf(fmaxf(s[0][r], s[1][r]), fmaxf(s[2][r], s[3][r]));
#pragma unroll
            for (int d = 1; d < 16; d <<= 1) mx = fmaxf(mx, __shfl_xor(mx, d));
            float mnew = fmaxf(m_run[r], mx);
            float alpha = __expf(m_run[r] - mnew);
            m_run[r] = mnew;
            float rs = 0.0f;
#pragma unroll
            for (int j = 0; j < 4; j++) {
                float p = __expf(s[j][r] - mnew);
                s[j][r] = p;
                rs += p;
            }
#pragma unroll
            for (int d = 1; d < 16; d <<= 1) rs += __shfl_xor(rs, d);
            l_run[r] = l_run[r] * alpha + rs;
#pragma unroll
            for (int j = 0; j < 4; j++) acc[j][r] *= alpha;
        }
        // P (C-layout) -> LDS, wave-private 16 rows; re-read as A-frags
#pragma unroll
        for (int j = 0; j < 4; j++)
#pragma unroll
            for (int r = 0; r < 4; r++)
                Ps[(wave << 4) + (lane >> 4) * 4 + r][j * 16 + (lane & 15)] = f2bf(s[j][r]);
        bfrag ap0 = *(const bfrag*)(&Ps[arow][koff]);
        bfrag ap1 = *(const bfrag*)(&Ps[arow][32 + koff]);
#pragma unroll
        for (int j = 0; j < 4; j++) {
            bfrag v0 = *(const bfrag*)(&Vts[j * 16 + (lane & 15)][koff]);
            acc[j] = __builtin_amdgcn_mfma_f32_16x16x32_bf16(ap0, v0, acc[j], 0, 0, 0);
            bfrag v1 = *(const bfrag*)(&Vts[j * 16 + (lane & 15)][32 + koff]);
            acc[j] = __builtin_amdgcn_mfma_f32_16x16x32_bf16(ap1, v1, acc[j], 0, 0, 0);
        }
    }
    int row0 = qc * 64 + (wave << 4) + (lane >> 4) * 4;
#pragma unroll
    for (int j = 0; j < 4; j++) {
        int col = hh * 64 + j * 16 + (lane & 15);
#pragma unroll
        for (int r = 0; r < 4; r++) {
            float val = acc[j][r] / l_run[r];
            o[((size_t)win * 512 + row0 + r) * 512 + col] = f2bf(val);
        }
    }
}

extern "C" void kernel_launch(void* const* d_in, const int* in_sizes, int n_in,
                              void* d_out, int out_size, void* d_ws, size_t ws_size,
                              hipStream_t stream) {
    const float* x      = (const float*)d_in[0];
    const float* q_ms   = (const float*)d_in[1];
    const float* n1w    = (const float*)d_in[2];
    const float* n1b    = (const float*)d_in[3];
    const float* kv_w   = (const float*)d_in[4];
    const float* kv_b   = (const float*)d_in[5];
    const float* proj_w = (const float*)d_in[6];
    const float* proj_b = (const float*)d_in[7];
    const float* n2w    = (const float*)d_in[8];
    const float* n2b    = (const float*)d_in[9];
    const float* fc1_w  = (const float*)d_in[10];
    const float* fc1_b  = (const float*)d_in[11];
    const float* fc2_w  = (const float*)d_in[12];
    const float* fc2_b  = (const float*)d_in[13];

    char* ws = (char*)d_ws;
    const size_t OFF_XNW = 0;           // bf16 [32768][512]   33,554,432 B
    const size_t OFF_KV  = 33554432;    // bf16 [32768][1024]  67,108,864 B
    const size_t OFF_O   = 100663296;   // bf16 [32768][512]   33,554,432 B
    const size_t OFF_HID = 0;           // bf16 [32768][2048] 134,217,728 B (aliases the 3 above; they are dead)
    const size_t OFF_X1  = 134217728;   // f32  [32768][512]   67,108,864 B
    const size_t OFF_XN2 = 201326592;   // bf16 [32768][512]   33,554,432 B
    const size_t OFF_W   = 234881024;   // transposed weights + q
    u16* xnw = (u16*)(ws + OFF_XNW);
    u16* kvb = (u16*)(ws + OFF_KV);
    u16* ob  = (u16*)(ws + OFF_O);
    u16* hid = (u16*)(ws + OFF_HID);
    float* x1 = (float*)(ws + OFF_X1);
    u16* xn2 = (u16*)(ws + OFF_XN2);
    u16* kv_wt   = (u16*)(ws + OFF_W);        // [1024][512]
    u16* proj_wt = kv_wt + 512 * 1024;        // [512][512]
    u16* fc1_wt  = proj_wt + 512 * 512;       // [2048][512]
    u16* fc2_wt  = fc1_wt + 512 * 2048;       // [512][2048]
    u16* qbf     = fc2_wt + 2048 * 512;       // [8][512][64]
    size_t need = OFF_W + (size_t)(512 * 1024 + 512 * 512 + 512 * 2048 + 2048 * 512 + 8 * 512 * 64) * 2;
    if (ws_size < need) return;  // ws too small; bail (will show as wrong output)

    k_ln<<<8192, 256, 0, stream>>>(x, n1w, n1b, xnw, 1);
    k_transpose<<<2048, 256, 0, stream>>>(kv_w, kv_wt, 512, 1024);
    k_transpose<<<1024, 256, 0, stream>>>(proj_w, proj_wt, 512, 512);
    k_transpose<<<4096, 256, 0, stream>>>(fc1_w, fc1_wt, 512, 2048);
    k_transpose<<<4096, 256, 0, stream>>>(fc2_w, fc2_wt, 2048, 512);
    k_qconv<<<1024, 256, 0, stream>>>(q_ms, qbf);

    k_gemm<0><<<dim3(512, 16), 256, 0, stream>>>(xnw, kv_wt, kv_b, kvb, 512, nullptr);
    k_attn<<<dim3(8, 8, 64), 256, 0, stream>>>(qbf, kvb, ob);
    k_gemm<1><<<dim3(512, 8), 256, 0, stream>>>(ob, proj_wt, proj_b, x1, 512, x);
    k_ln<<<8192, 256, 0, stream>>>(x1, n2w, n2b, xn2, 0);
    k_gemm<2><<<dim3(512, 32), 256, 0, stream>>>(xn2, fc1_wt, fc1_b, hid, 512, nullptr);
    k_gemm<3><<<dim3(512, 8), 256, 0, stream>>>(hid, fc2_wt, fc2_b, d_out, 2048, x1);
}

// Round 2
// 683.202 us; speedup vs baseline: 1.1077x; 1.1077x over previous
//
#include <hip/hip_runtime.h>

typedef unsigned short u16;
typedef __attribute__((ext_vector_type(8))) short bfrag;   // 8 x bf16
typedef __attribute__((ext_vector_type(4))) float ffrag;   // 4 x f32

#define LN_EPS 1e-5f

#define GLOAD16(g, l)                                                          \
    __builtin_amdgcn_global_load_lds(                                          \
        (const __attribute__((address_space(1))) void*)(g),                    \
        (__attribute__((address_space(3))) void*)(l), 16, 0, 0)

__device__ __forceinline__ u16 f2bf(float f) {
    unsigned u = __builtin_bit_cast(unsigned, f);
    u += 0x7fffu + ((u >> 16) & 1u);   // RNE
    return (u16)(u >> 16);
}

// windowed token index -> image row index
__device__ __forceinline__ int win_to_img(int tok) {
    int win = tok >> 9, n = tok & 511;
    int wh = win >> 4, ww = (win >> 2) & 3, wd = win & 3;
    int ph = n >> 6, pw = (n >> 3) & 7, pd = n & 7;
    return ((wh * 8 + ph) * 32 + (ww * 8 + pw)) * 32 + (wd * 8 + pd);
}

// LayerNorm over C=512, one wave per token. windowed=1: read image order at
// gathered index, write windowed order. windowed=0: straight rows.
__global__ __launch_bounds__(256) void k_ln(const float* __restrict__ x,
                                            const float* __restrict__ w,
                                            const float* __restrict__ b,
                                            u16* __restrict__ out, int windowed) {
    int wave = threadIdx.x >> 6, lane = threadIdx.x & 63;
    int tok = blockIdx.x * 4 + wave;
    int src = windowed ? win_to_img(tok) : tok;
    const float* xr = x + (size_t)src * 512;
    float v[8];
#pragma unroll
    for (int i = 0; i < 2; i++) {
        float4 f = *(const float4*)(xr + i * 256 + lane * 4);
        v[i * 4 + 0] = f.x; v[i * 4 + 1] = f.y; v[i * 4 + 2] = f.z; v[i * 4 + 3] = f.w;
    }
    float s = 0.f;
#pragma unroll
    for (int i = 0; i < 8; i++) s += v[i];
#pragma unroll
    for (int m = 1; m < 64; m <<= 1) s += __shfl_xor(s, m);
    float mean = s * (1.0f / 512.0f);
    float vs = 0.f;
#pragma unroll
    for (int i = 0; i < 8; i++) { float d = v[i] - mean; vs += d * d; }
#pragma unroll
    for (int m = 1; m < 64; m <<= 1) vs += __shfl_xor(vs, m);
    float rstd = rsqrtf(vs * (1.0f / 512.0f) + LN_EPS);
    u16* orow = out + (size_t)tok * 512;
#pragma unroll
    for (int i = 0; i < 2; i++) {
        int c0 = i * 256 + lane * 4;
        ushort4 o;
        o.x = f2bf((v[i * 4 + 0] - mean) * rstd * w[c0 + 0] + b[c0 + 0]);
        o.y = f2bf((v[i * 4 + 1] - mean) * rstd * w[c0 + 1] + b[c0 + 1]);
        o.z = f2bf((v[i * 4 + 2] - mean) * rstd * w[c0 + 2] + b[c0 + 2]);
        o.w = f2bf((v[i * 4 + 3] - mean) * rstd * w[c0 + 3] + b[c0 + 3]);
        *(ushort4*)(orow + c0) = o;
    }
}

// in: f32 [K][Nn] row-major  ->  out: bf16 [Nn][K] (K contiguous)
__global__ __launch_bounds__(256) void k_transpose(const float* __restrict__ in,
                                                   u16* __restrict__ out, int K, int Nn) {
    int idx = blockIdx.x * 256 + threadIdx.x;
    if (idx >= K * Nn) return;
    int n = idx / K, k = idx - n * K;
    out[idx] = f2bf(in[(size_t)k * Nn + n]);
}

// q_ms f32 [8][512][64] -> bf16, pre-scaled by HD^-0.5 = 0.125
__global__ __launch_bounds__(256) void k_qconv(const float* __restrict__ q, u16* __restrict__ out) {
    int idx = blockIdx.x * 256 + threadIdx.x;
    out[idx] = f2bf(q[idx] * 0.125f);
}

// C = A[M,K](bf16,K-contig) @ Bt[Nn,K](bf16,K-contig)^T + bias. m97 structure:
// 128x128 tile, BK=32, 4 waves (2x2) each 64x64 out, global_load_lds w=16.
// EPI 0: +bias -> bf16                                       (kv)
// EPI 1: +bias, scatter windowed->image, + resid(x) -> f32   (proj -> x1)
// EPI 2: +bias, exact GELU -> bf16                           (fc1 -> hid)
// EPI 3: +bias, + resid(x1) -> f32                           (fc2 -> out)
template <int EPI>
__global__ __launch_bounds__(256) void k_gemm128(const u16* __restrict__ A,
                                                 const u16* __restrict__ Bt,
                                                 const float* __restrict__ bias,
                                                 void* __restrict__ Cout, int K, int Nn,
                                                 const float* __restrict__ resid) {
    __shared__ u16 As[128][32];   // linear: required by global_load_lds scatter
    __shared__ u16 Bs[128][32];
    int tid = threadIdx.x;
    int wave = tid >> 6, lane = tid & 63;
    int wr = wave >> 1, wc = wave & 1;
    int bm = blockIdx.x, bn = blockIdx.y;

    // staging: wave w covers LDS rows [w*32, w*32+32), two 16-row insts/matrix.
    // lane l -> row w*32 (+16) + (l>>2), k = (l&3)*8  (matches base + l*16 bytes)
    int srow = wave * 32 + (lane >> 2);
    int sk = (lane & 3) * 8;
    const u16* Ag = A + (size_t)(bm * 128 + srow) * K + sk;
    const u16* Bg = Bt + (size_t)(bn * 128 + srow) * K + sk;
    u16* AsD0 = &As[wave * 32][0];
    u16* AsD1 = &As[wave * 32 + 16][0];
    u16* BsD0 = &Bs[wave * 32][0];
    u16* BsD1 = &Bs[wave * 32 + 16][0];

    ffrag acc[4][4] = {};
    int fr = lane & 15;
    int fk = (lane >> 4) * 8;

    for (int k0 = 0; k0 < K; k0 += 32) {
        GLOAD16(Ag + k0, AsD0);
        GLOAD16(Ag + k0 + (size_t)16 * K, AsD1);
        GLOAD16(Bg + k0, BsD0);
        GLOAD16(Bg + k0 + (size_t)16 * K, BsD1);
        __syncthreads();   // vmcnt(0) drain + barrier: tile ready
        bfrag a[4], b[4];
#pragma unroll
        for (int m = 0; m < 4; m++) a[m] = *(const bfrag*)(&As[wr * 64 + m * 16 + fr][fk]);
#pragma unroll
        for (int n = 0; n < 4; n++) b[n] = *(const bfrag*)(&Bs[wc * 64 + n * 16 + fr][fk]);
#pragma unroll
        for (int m = 0; m < 4; m++)
#pragma unroll
            for (int n = 0; n < 4; n++)
                acc[m][n] = __builtin_amdgcn_mfma_f32_16x16x32_bf16(a[m], b[n], acc[m][n], 0, 0, 0);
        __syncthreads();   // reads done before next stage overwrites
    }

    int row0 = bm * 128 + wr * 64 + (lane >> 4) * 4;
    int col0 = bn * 128 + wc * 64 + (lane & 15);
#pragma unroll
    for (int n = 0; n < 4; n++) {
        int col = col0 + n * 16;
        float bv = bias[col];
#pragma unroll
        for (int m = 0; m < 4; m++) {
#pragma unroll
            for (int r = 0; r < 4; r++) {
                int row = row0 + m * 16 + r;
                float val = acc[m][n][r] + bv;
                if constexpr (EPI == 0) {
                    ((u16*)Cout)[(size_t)row * Nn + col] = f2bf(val);
                } else if constexpr (EPI == 1) {
                    int ri = win_to_img(row);
                    size_t o = (size_t)ri * 512 + col;
                    ((float*)Cout)[o] = val + resid[o];
                } else if constexpr (EPI == 2) {
                    val = 0.5f * val * (1.0f + erff(val * 0.70710678118f));
                    ((u16*)Cout)[(size_t)row * Nn + col] = f2bf(val);
                } else {
                    size_t o = (size_t)row * 512 + col;
                    ((float*)Cout)[o] = val + resid[o];
                }
            }
        }
    }
}

// Flash attention: block = (q-chunk 64, head, window), 4 waves x 16 q-rows.
// qb: bf16 [8][512][64] (pre-scaled); kv: bf16 [32768][1024] (k | v per token);
// o: bf16 [32768][512] (windowed token order).
__global__ __launch_bounds__(256) void k_attn(const u16* __restrict__ qb,
                                              const u16* __restrict__ kv,
                                              u16* __restrict__ o) {
    __shared__ u16 Ks[64][72];    // [key][d]   144B stride: aligned, 2-way alias
    __shared__ u16 Vts[64][72];   // [d][key]
    __shared__ u16 Ps[64][72];    // [q][key]   wave-private row blocks
    int qc = blockIdx.x, hh = blockIdx.y, win = blockIdx.z;
    int wave = threadIdx.x >> 6, lane = threadIdx.x & 63;
    int t = threadIdx.x;
    const u16* qrow = qb + ((size_t)hh * 512 + qc * 64 + (wave << 4) + (lane & 15)) * 64 + (lane >> 4) * 8;
    bfrag aq0 = *(const bfrag*)(qrow);
    bfrag aq1 = *(const bfrag*)(qrow + 32);
    ffrag acc[4] = {};
    float m_run[4], l_run[4];
#pragma unroll
    for (int r = 0; r < 4; r++) { m_run[r] = -1e30f; l_run[r] = 0.0f; }
    const u16* kvw = kv + (size_t)win * 512 * 1024;
    int krow = t >> 2, kco = (t & 3) * 8;
    int vkt = t >> 2, vdb = (t & 3) * 16;
    int arow = (wave << 4) + (lane & 15);
    int koff = (lane >> 4) * 8;

    for (int kc = 0; kc < 8; kc++) {
        __syncthreads();   // prior iteration's K/V reads complete
        const u16* ksrc = kvw + (size_t)(kc * 64 + krow) * 1024 + hh * 64 + kco;
        *(int4*)(&Ks[krow][kco]) = *(const int4*)(ksrc);
        *(int4*)(&Ks[krow][kco + 32]) = *(const int4*)(ksrc + 32);
        const u16* vsrc = kvw + (size_t)(kc * 64 + vkt) * 1024 + 512 + hh * 64 + vdb;
        alignas(16) u16 tmp[16];
        *(int4*)(tmp) = *(const int4*)(vsrc);
        *(int4*)(tmp + 8) = *(const int4*)(vsrc + 8);
#pragma unroll
        for (int i = 0; i < 16; i++) Vts[vdb + i][vkt] = tmp[i];
        __syncthreads();

        ffrag s[4] = {};
#pragma unroll
        for (int j = 0; j < 4; j++) {
            bfrag b0 = *(const bfrag*)(&Ks[j * 16 + (lane & 15)][koff]);
            s[j] = __builtin_amdgcn_mfma_f32_16x16x32_bf16(aq0, b0, s[j], 0, 0, 0);
            bfrag b1 = *(const bfrag*)(&Ks[j * 16 + (lane & 15)][32 + koff]);
            s[j] = __builtin_amdgcn_mfma_f32_16x16x32_bf16(aq1, b1, s[j], 0, 0, 0);
        }
        // online softmax per q-row (row = (lane>>4)*4 + r; cols across 16 lanes x 4 frags)
#pragma unroll
        for (int r = 0; r < 4; r++) {
            float mx = fmaxf(fmaxf(s[0][r], s[1][r]), fmaxf(s[2][r], s[3][r]));
#pragma unroll
            for (int d = 1; d < 16; d <<= 1) mx = fmaxf(mx, __shfl_xor(mx, d));
            float mnew = fmaxf(m_run[r], mx);
            float alpha = __expf(m_run[r] - mnew);
            m_run[r] = mnew;
            float rs = 0.0f;
#pragma unroll
            for (int j = 0; j < 4; j++) {
                float p = __expf(s[j][r] - mnew);
                s[j][r] = p;
                rs += p;
            }
#pragma unroll
            for (int d = 1; d < 16; d <<= 1) rs += __shfl_xor(rs, d);
            l_run[r] = l_run[r] * alpha + rs;
#pragma unroll
            for (int j = 0; j < 4; j++) acc[j][r] *= alpha;
        }
        // P (C-layout) -> LDS, wave-private 16 rows; re-read as A-frags
#pragma unroll
        for (int j = 0; j < 4; j++)
#pragma unroll
            for (int r = 0; r < 4; r++)
                Ps[(wave << 4) + (lane >> 4) * 4 + r][j * 16 + (lane & 15)] = f2bf(s[j][r]);
        bfrag ap0 = *(const bfrag*)(&Ps[arow][koff]);
        bfrag ap1 = *(const bfrag*)(&Ps[arow][32 + koff]);
#pragma unroll
        for (int j = 0; j < 4; j++) {
            bfrag v0 = *(const bfrag*)(&Vts[j * 16 + (lane & 15)][koff]);
            acc[j] = __builtin_amdgcn_mfma_f32_16x16x32_bf16(ap0, v0, acc[j], 0, 0, 0);
            bfrag v1 = *(const bfrag*)(&Vts[j * 16 + (lane & 15)][32 + koff]);
            acc[j] = __builtin_amdgcn_mfma_f32_16x16x32_bf16(ap1, v1, acc[j], 0, 0, 0);
        }
    }
    int row0 = qc * 64 + (wave << 4) + (lane >> 4) * 4;
#pragma unroll
    for (int j = 0; j < 4; j++) {
        int col = hh * 64 + j * 16 + (lane & 15);
#pragma unroll
        for (int r = 0; r < 4; r++) {
            float val = acc[j][r] / l_run[r];
            o[((size_t)win * 512 + row0 + r) * 512 + col] = f2bf(val);
        }
    }
}

extern "C" void kernel_launch(void* const* d_in, const int* in_sizes, int n_in,
                              void* d_out, int out_size, void* d_ws, size_t ws_size,
                              hipStream_t stream) {
    const float* x      = (const float*)d_in[0];
    const float* q_ms   = (const float*)d_in[1];
    const float* n1w    = (const float*)d_in[2];
    const float* n1b    = (const float*)d_in[3];
    const float* kv_w   = (const float*)d_in[4];
    const float* kv_b   = (const float*)d_in[5];
    const float* proj_w = (const float*)d_in[6];
    const float* proj_b = (const float*)d_in[7];
    const float* n2w    = (const float*)d_in[8];
    const float* n2b    = (const float*)d_in[9];
    const float* fc1_w  = (const float*)d_in[10];
    const float* fc1_b  = (const float*)d_in[11];
    const float* fc2_w  = (const float*)d_in[12];
    const float* fc2_b  = (const float*)d_in[13];

    char* ws = (char*)d_ws;
    const size_t OFF_XNW = 0;           // bf16 [32768][512]   33,554,432 B
    const size_t OFF_KV  = 33554432;    // bf16 [32768][1024]  67,108,864 B
    const size_t OFF_O   = 100663296;   // bf16 [32768][512]   33,554,432 B
    const size_t OFF_HID = 0;           // bf16 [32768][2048] 134,217,728 B (aliases the 3 above; they are dead)
    const size_t OFF_X1  = 134217728;   // f32  [32768][512]   67,108,864 B
    const size_t OFF_XN2 = 201326592;   // bf16 [32768][512]   33,554,432 B
    const size_t OFF_W   = 234881024;   // transposed weights + q
    u16* xnw = (u16*)(ws + OFF_XNW);
    u16* kvb = (u16*)(ws + OFF_KV);
    u16* ob  = (u16*)(ws + OFF_O);
    u16* hid = (u16*)(ws + OFF_HID);
    float* x1 = (float*)(ws + OFF_X1);
    u16* xn2 = (u16*)(ws + OFF_XN2);
    u16* kv_wt   = (u16*)(ws + OFF_W);        // [1024][512]
    u16* proj_wt = kv_wt + 512 * 1024;        // [512][512]
    u16* fc1_wt  = proj_wt + 512 * 512;       // [2048][512]
    u16* fc2_wt  = fc1_wt + 512 * 2048;       // [512][2048]
    u16* qbf     = fc2_wt + 2048 * 512;       // [8][512][64]
    size_t need = OFF_W + (size_t)(512 * 1024 + 512 * 512 + 512 * 2048 + 2048 * 512 + 8 * 512 * 64) * 2;
    if (ws_size < need) return;  // ws too small; bail (will show as wrong output)

    k_ln<<<8192, 256, 0, stream>>>(x, n1w, n1b, xnw, 1);
    k_transpose<<<2048, 256, 0, stream>>>(kv_w, kv_wt, 512, 1024);
    k_transpose<<<1024, 256, 0, stream>>>(proj_w, proj_wt, 512, 512);
    k_transpose<<<4096, 256, 0, stream>>>(fc1_w, fc1_wt, 512, 2048);
    k_transpose<<<4096, 256, 0, stream>>>(fc2_w, fc2_wt, 2048, 512);
    k_qconv<<<1024, 256, 0, stream>>>(q_ms, qbf);

    k_gemm128<0><<<dim3(256, 8), 256, 0, stream>>>(xnw, kv_wt, kv_b, kvb, 512, 1024, nullptr);
    k_attn<<<dim3(8, 8, 64), 256, 0, stream>>>(qbf, kvb, ob);
    k_gemm128<1><<<dim3(256, 4), 256, 0, stream>>>(ob, proj_wt, proj_b, x1, 512, 512, x);
    k_ln<<<8192, 256, 0, stream>>>(x1, n2w, n2b, xn2, 0);
    k_gemm128<2><<<dim3(256, 16), 256, 0, stream>>>(xn2, fc1_wt, fc1_b, hid, 512, 2048, nullptr);
    k_gemm128<3><<<dim3(256, 4), 256, 0, stream>>>(hid, fc2_wt, fc2_b, d_out, 2048, 512, x1);
}

// Round 3
// 570.817 us; speedup vs baseline: 1.3257x; 1.1969x over previous
//
#include <hip/hip_runtime.h>

typedef unsigned short u16;
typedef __attribute__((ext_vector_type(8))) short bfrag;   // 8 x bf16
typedef __attribute__((ext_vector_type(4))) float ffrag;   // 4 x f32

#define LN_EPS 1e-5f

#define GLOAD16(g, l)                                                          \
    __builtin_amdgcn_global_load_lds(                                          \
        (const __attribute__((address_space(1))) void*)(g),                    \
        (__attribute__((address_space(3))) void*)(l), 16, 0, 0)

__device__ __forceinline__ u16 f2bf(float f) {
    unsigned u = __builtin_bit_cast(unsigned, f);
    u += 0x7fffu + ((u >> 16) & 1u);   // RNE
    return (u16)(u >> 16);
}

// windowed token index -> image row index
__device__ __forceinline__ int win_to_img(int tok) {
    int win = tok >> 9, n = tok & 511;
    int wh = win >> 4, ww = (win >> 2) & 3, wd = win & 3;
    int ph = n >> 6, pw = (n >> 3) & 7, pd = n & 7;
    return ((wh * 8 + ph) * 32 + (ww * 8 + pw)) * 32 + (wd * 8 + pd);
}

// LayerNorm over C=512, one wave per token. windowed=1: read image order at
// gathered index, write windowed order. windowed=0: straight rows.
__global__ __launch_bounds__(256) void k_ln(const float* __restrict__ x,
                                            const float* __restrict__ w,
                                            const float* __restrict__ b,
                                            u16* __restrict__ out, int windowed) {
    int wave = threadIdx.x >> 6, lane = threadIdx.x & 63;
    int tok = blockIdx.x * 4 + wave;
    int src = windowed ? win_to_img(tok) : tok;
    const float* xr = x + (size_t)src * 512;
    float v[8];
#pragma unroll
    for (int i = 0; i < 2; i++) {
        float4 f = *(const float4*)(xr + i * 256 + lane * 4);
        v[i * 4 + 0] = f.x; v[i * 4 + 1] = f.y; v[i * 4 + 2] = f.z; v[i * 4 + 3] = f.w;
    }
    float s = 0.f;
#pragma unroll
    for (int i = 0; i < 8; i++) s += v[i];
#pragma unroll
    for (int m = 1; m < 64; m <<= 1) s += __shfl_xor(s, m);
    float mean = s * (1.0f / 512.0f);
    float vs = 0.f;
#pragma unroll
    for (int i = 0; i < 8; i++) { float d = v[i] - mean; vs += d * d; }
#pragma unroll
    for (int m = 1; m < 64; m <<= 1) vs += __shfl_xor(vs, m);
    float rstd = rsqrtf(vs * (1.0f / 512.0f) + LN_EPS);
    u16* orow = out + (size_t)tok * 512;
#pragma unroll
    for (int i = 0; i < 2; i++) {
        int c0 = i * 256 + lane * 4;
        ushort4 o;
        o.x = f2bf((v[i * 4 + 0] - mean) * rstd * w[c0 + 0] + b[c0 + 0]);
        o.y = f2bf((v[i * 4 + 1] - mean) * rstd * w[c0 + 1] + b[c0 + 1]);
        o.z = f2bf((v[i * 4 + 2] - mean) * rstd * w[c0 + 2] + b[c0 + 2]);
        o.w = f2bf((v[i * 4 + 3] - mean) * rstd * w[c0 + 3] + b[c0 + 3]);
        *(ushort4*)(orow + c0) = o;
    }
}

// in: f32 [K][Nn] row-major  ->  out: bf16 [Nn][K] (K contiguous)
__global__ __launch_bounds__(256) void k_transpose(const float* __restrict__ in,
                                                   u16* __restrict__ out, int K, int Nn) {
    int idx = blockIdx.x * 256 + threadIdx.x;
    if (idx >= K * Nn) return;
    int n = idx / K, k = idx - n * K;
    out[idx] = f2bf(in[(size_t)k * Nn + n]);
}

// q_ms f32 [8][512][64] -> bf16, pre-scaled by HD^-0.5 = 0.125
__global__ __launch_bounds__(256) void k_qconv(const float* __restrict__ q, u16* __restrict__ out) {
    int idx = blockIdx.x * 256 + threadIdx.x;
    out[idx] = f2bf(q[idx] * 0.125f);
}

// C = A[M,K](bf16,K-contig) @ Bt[Nn,K](bf16,K-contig)^T + bias.
// 128x128 tile, BK=32, 4 waves (2x2) each 64x64 out, global_load_lds w=16,
// 2-phase double-buffer (T3-minimal): stage tile t+1 before computing tile t,
// one __syncthreads (vmcnt0+lgkm0+barrier) per K-step. Static buffers so
// alias analysis can't inject a vmcnt wait before the compute ds_reads.
// grid: x = N-blocks (panel-sharing blocks adjacent), y = M-blocks.
// EPI 0: +bias -> bf16                                       (kv)
// EPI 1: +bias, scatter windowed->image, + resid(x) -> f32   (proj -> x1)
// EPI 2: +bias, exact GELU -> bf16                           (fc1 -> hid)
// EPI 3: +bias, + resid(x1) -> f32                           (fc2 -> out)
template <int EPI>
__global__ __launch_bounds__(256, 4) void k_gemm128(const u16* __restrict__ A,
                                                    const u16* __restrict__ Bt,
                                                    const float* __restrict__ bias,
                                                    void* __restrict__ Cout, int K, int Nn,
                                                    const float* __restrict__ resid) {
    __shared__ u16 As0[128][32], Bs0[128][32];
    __shared__ u16 As1[128][32], Bs1[128][32];
    int tid = threadIdx.x;
    int wave = tid >> 6, lane = tid & 63;
    int wr = wave >> 1, wc = wave & 1;
    int bn = blockIdx.x, bm = blockIdx.y;

    // staging: wave w covers LDS rows [w*32, w*32+32), two 16-row insts/matrix.
    // lane l -> row w*32 (+16) + (l>>2), k = (l&3)*8  (matches base + l*16 bytes)
    int srow = wave * 32 + (lane >> 2);
    int sk = (lane & 3) * 8;
    const u16* Ag = A + (size_t)(bm * 128 + srow) * K + sk;
    const u16* Bg = Bt + (size_t)(bn * 128 + srow) * K + sk;

    ffrag acc[4][4] = {};
    int fr = lane & 15;
    int fk = (lane >> 4) * 8;

#define STAGE(AS, BS, k0)                                                      \
    {                                                                          \
        GLOAD16(Ag + (k0), &AS[wave * 32][0]);                                 \
        GLOAD16(Ag + (k0) + 16 * K, &AS[wave * 32 + 16][0]);                   \
        GLOAD16(Bg + (k0), &BS[wave * 32][0]);                                 \
        GLOAD16(Bg + (k0) + 16 * K, &BS[wave * 32 + 16][0]);                   \
    }
#define COMPUTE(AS, BS)                                                        \
    {                                                                          \
        bfrag a[4], b[4];                                                      \
        _Pragma("unroll") for (int m = 0; m < 4; m++)                          \
            a[m] = *(const bfrag*)(&AS[wr * 64 + m * 16 + fr][fk]);            \
        _Pragma("unroll") for (int n = 0; n < 4; n++)                          \
            b[n] = *(const bfrag*)(&BS[wc * 64 + n * 16 + fr][fk]);            \
        _Pragma("unroll") for (int m = 0; m < 4; m++)                          \
            _Pragma("unroll") for (int n = 0; n < 4; n++)                      \
                acc[m][n] = __builtin_amdgcn_mfma_f32_16x16x32_bf16(           \
                    a[m], b[n], acc[m][n], 0, 0, 0);                           \
    }

    int nt = K >> 5;   // K-steps of 32; even for all our K
    STAGE(As0, Bs0, 0);
    __syncthreads();
    int t = 0;
    for (; t + 2 < nt; t += 2) {
        STAGE(As1, Bs1, (t + 1) * 32);
        COMPUTE(As0, Bs0);
        __syncthreads();
        STAGE(As0, Bs0, (t + 2) * 32);
        COMPUTE(As1, Bs1);
        __syncthreads();
    }
    // t == nt-2
    STAGE(As1, Bs1, (nt - 1) * 32);
    COMPUTE(As0, Bs0);
    __syncthreads();
    COMPUTE(As1, Bs1);
#undef STAGE
#undef COMPUTE

    int row0 = bm * 128 + wr * 64 + (lane >> 4) * 4;
    int col0 = bn * 128 + wc * 64 + (lane & 15);
#pragma unroll
    for (int n = 0; n < 4; n++) {
        int col = col0 + n * 16;
        float bv = bias[col];
#pragma unroll
        for (int m = 0; m < 4; m++) {
#pragma unroll
            for (int r = 0; r < 4; r++) {
                int row = row0 + m * 16 + r;
                float val = acc[m][n][r] + bv;
                if constexpr (EPI == 0) {
                    ((u16*)Cout)[(size_t)row * Nn + col] = f2bf(val);
                } else if constexpr (EPI == 1) {
                    int ri = win_to_img(row);
                    size_t o = (size_t)ri * 512 + col;
                    ((float*)Cout)[o] = val + resid[o];
                } else if constexpr (EPI == 2) {
                    val = 0.5f * val * (1.0f + erff(val * 0.70710678118f));
                    ((u16*)Cout)[(size_t)row * Nn + col] = f2bf(val);
                } else {
                    size_t o = (size_t)row * 512 + col;
                    ((float*)Cout)[o] = val + resid[o];
                }
            }
        }
    }
}

// Flash attention: block = (q-chunk 64, head, window), 4 waves x 16 q-rows.
// qb: bf16 [8][512][64] (pre-scaled); kv: bf16 [32768][1024] (k | v per token);
// o: bf16 [32768][512] (windowed token order).
__global__ __launch_bounds__(256) void k_attn(const u16* __restrict__ qb,
                                              const u16* __restrict__ kv,
                                              u16* __restrict__ o) {
    __shared__ u16 Ks[64][72];    // [key][d]   144B stride: aligned, 2-way alias
    __shared__ u16 Vts[64][72];   // [d][key]
    __shared__ u16 Ps[64][72];    // [q][key]   wave-private row blocks
    int qc = blockIdx.x, hh = blockIdx.y, win = blockIdx.z;
    int wave = threadIdx.x >> 6, lane = threadIdx.x & 63;
    int t = threadIdx.x;
    const u16* qrow = qb + ((size_t)hh * 512 + qc * 64 + (wave << 4) + (lane & 15)) * 64 + (lane >> 4) * 8;
    bfrag aq0 = *(const bfrag*)(qrow);
    bfrag aq1 = *(const bfrag*)(qrow + 32);
    ffrag acc[4] = {};
    float m_run[4], l_run[4];
#pragma unroll
    for (int r = 0; r < 4; r++) { m_run[r] = -1e30f; l_run[r] = 0.0f; }
    const u16* kvw = kv + (size_t)win * 512 * 1024;
    int krow = t >> 2, kco = (t & 3) * 8;
    int vkt = t >> 2, vdb = (t & 3) * 16;
    int arow = (wave << 4) + (lane & 15);
    int koff = (lane >> 4) * 8;

    for (int kc = 0; kc < 8; kc++) {
        __syncthreads();   // prior iteration's K/V reads complete
        const u16* ksrc = kvw + (size_t)(kc * 64 + krow) * 1024 + hh * 64 + kco;
        *(int4*)(&Ks[krow][kco]) = *(const int4*)(ksrc);
        *(int4*)(&Ks[krow][kco + 32]) = *(const int4*)(ksrc + 32);
        const u16* vsrc = kvw + (size_t)(kc * 64 + vkt) * 1024 + 512 + hh * 64 + vdb;
        alignas(16) u16 tmp[16];
        *(int4*)(tmp) = *(const int4*)(vsrc);
        *(int4*)(tmp + 8) = *(const int4*)(vsrc + 8);
#pragma unroll
        for (int i = 0; i < 16; i++) Vts[vdb + i][vkt] = tmp[i];
        __syncthreads();

        ffrag s[4] = {};
#pragma unroll
        for (int j = 0; j < 4; j++) {
            bfrag b0 = *(const bfrag*)(&Ks[j * 16 + (lane & 15)][koff]);
            s[j] = __builtin_amdgcn_mfma_f32_16x16x32_bf16(aq0, b0, s[j], 0, 0, 0);
            bfrag b1 = *(const bfrag*)(&Ks[j * 16 + (lane & 15)][32 + koff]);
            s[j] = __builtin_amdgcn_mfma_f32_16x16x32_bf16(aq1, b1, s[j], 0, 0, 0);
        }
        // online softmax per q-row (row = (lane>>4)*4 + r; cols across 16 lanes x 4 frags)
#pragma unroll
        for (int r = 0; r < 4; r++) {
            float mx = fmaxf(fmaxf(s[0][r], s[1][r]), fmaxf(s[2][r], s[3][r]));
#pragma unroll
            for (int d = 1; d < 16; d <<= 1) mx = fmaxf(mx, __shfl_xor(mx, d));
            float mnew = fmaxf(m_run[r], mx);
            float alpha = __expf(m_run[r] - mnew);
            m_run[r] = mnew;
            float rs = 0.0f;
#pragma unroll
            for (int j = 0; j < 4; j++) {
                float p = __expf(s[j][r] - mnew);
                s[j][r] = p;
                rs += p;
            }
#pragma unroll
            for (int d = 1; d < 16; d <<= 1) rs += __shfl_xor(rs, d);
            l_run[r] = l_run[r] * alpha + rs;
#pragma unroll
            for (int j = 0; j < 4; j++) acc[j][r] *= alpha;
        }
        // P (C-layout) -> LDS, wave-private 16 rows; re-read as A-frags
#pragma unroll
        for (int j = 0; j < 4; j++)
#pragma unroll
            for (int r = 0; r < 4; r++)
                Ps[(wave << 4) + (lane >> 4) * 4 + r][j * 16 + (lane & 15)] = f2bf(s[j][r]);
        bfrag ap0 = *(const bfrag*)(&Ps[arow][koff]);
        bfrag ap1 = *(const bfrag*)(&Ps[arow][32 + koff]);
#pragma unroll
        for (int j = 0; j < 4; j++) {
            bfrag v0 = *(const bfrag*)(&Vts[j * 16 + (lane & 15)][koff]);
            acc[j] = __builtin_amdgcn_mfma_f32_16x16x32_bf16(ap0, v0, acc[j], 0, 0, 0);
            bfrag v1 = *(const bfrag*)(&Vts[j * 16 + (lane & 15)][32 + koff]);
            acc[j] = __builtin_amdgcn_mfma_f32_16x16x32_bf16(ap1, v1, acc[j], 0, 0, 0);
        }
    }
    int row0 = qc * 64 + (wave << 4) + (lane >> 4) * 4;
#pragma unroll
    for (int j = 0; j < 4; j++) {
        int col = hh * 64 + j * 16 + (lane & 15);
#pragma unroll
        for (int r = 0; r < 4; r++) {
            float val = acc[j][r] / l_run[r];
            o[((size_t)win * 512 + row0 + r) * 512 + col] = f2bf(val);
        }
    }
}

extern "C" void kernel_launch(void* const* d_in, const int* in_sizes, int n_in,
                              void* d_out, int out_size, void* d_ws, size_t ws_size,
                              hipStream_t stream) {
    const float* x      = (const float*)d_in[0];
    const float* q_ms   = (const float*)d_in[1];
    const float* n1w    = (const float*)d_in[2];
    const float* n1b    = (const float*)d_in[3];
    const float* kv_w   = (const float*)d_in[4];
    const float* kv_b   = (const float*)d_in[5];
    const float* proj_w = (const float*)d_in[6];
    const float* proj_b = (const float*)d_in[7];
    const float* n2w    = (const float*)d_in[8];
    const float* n2b    = (const float*)d_in[9];
    const float* fc1_w  = (const float*)d_in[10];
    const float* fc1_b  = (const float*)d_in[11];
    const float* fc2_w  = (const float*)d_in[12];
    const float* fc2_b  = (const float*)d_in[13];

    char* ws = (char*)d_ws;
    const size_t OFF_XNW = 0;           // bf16 [32768][512]   33,554,432 B
    const size_t OFF_KV  = 33554432;    // bf16 [32768][1024]  67,108,864 B
    const size_t OFF_O   = 100663296;   // bf16 [32768][512]   33,554,432 B
    const size_t OFF_HID = 0;           // bf16 [32768][2048] 134,217,728 B (aliases the 3 above; they are dead)
    const size_t OFF_X1  = 134217728;   // f32  [32768][512]   67,108,864 B
    const size_t OFF_XN2 = 201326592;   // bf16 [32768][512]   33,554,432 B
    const size_t OFF_W   = 234881024;   // transposed weights + q
    u16* xnw = (u16*)(ws + OFF_XNW);
    u16* kvb = (u16*)(ws + OFF_KV);
    u16* ob  = (u16*)(ws + OFF_O);
    u16* hid = (u16*)(ws + OFF_HID);
    float* x1 = (float*)(ws + OFF_X1);
    u16* xn2 = (u16*)(ws + OFF_XN2);
    u16* kv_wt   = (u16*)(ws + OFF_W);        // [1024][512]
    u16* proj_wt = kv_wt + 512 * 1024;        // [512][512]
    u16* fc1_wt  = proj_wt + 512 * 512;       // [2048][512]
    u16* fc2_wt  = fc1_wt + 512 * 2048;       // [512][2048]
    u16* qbf     = fc2_wt + 2048 * 512;       // [8][512][64]
    size_t need = OFF_W + (size_t)(512 * 1024 + 512 * 512 + 512 * 2048 + 2048 * 512 + 8 * 512 * 64) * 2;
    if (ws_size < need) return;  // ws too small; bail (will show as wrong output)

    k_ln<<<8192, 256, 0, stream>>>(x, n1w, n1b, xnw, 1);
    k_transpose<<<2048, 256, 0, stream>>>(kv_w, kv_wt, 512, 1024);
    k_transpose<<<1024, 256, 0, stream>>>(proj_w, proj_wt, 512, 512);
    k_transpose<<<4096, 256, 0, stream>>>(fc1_w, fc1_wt, 512, 2048);
    k_transpose<<<4096, 256, 0, stream>>>(fc2_w, fc2_wt, 2048, 512);
    k_qconv<<<1024, 256, 0, stream>>>(q_ms, qbf);

    k_gemm128<0><<<dim3(8, 256), 256, 0, stream>>>(xnw, kv_wt, kv_b, kvb, 512, 1024, nullptr);
    k_attn<<<dim3(8, 8, 64), 256, 0, stream>>>(qbf, kvb, ob);
    k_gemm128<1><<<dim3(4, 256), 256, 0, stream>>>(ob, proj_wt, proj_b, x1, 512, 512, x);
    k_ln<<<8192, 256, 0, stream>>>(x1, n2w, n2b, xn2, 0);
    k_gemm128<2><<<dim3(16, 256), 256, 0, stream>>>(xn2, fc1_wt, fc1_b, hid, 512, 2048, nullptr);
    k_gemm128<3><<<dim3(4, 256), 256, 0, stream>>>(hid, fc2_wt, fc2_b, d_out, 2048, 512, x1);
}